// Round 5
// baseline (126.038 us; speedup 1.0000x reference)
//
#include <hip/hip_runtime.h>
#include <math.h>

#define BN_EPS 1e-5f

constexpr int B_ = 4, N_ = 16384, C_ = 64, K_ = 16, O_ = 64;
constexpr int ROWS = B_ * N_;            // 65536
constexpr int ROWS_PER_BLK = 64;
constexpr int NBLK_AB = ROWS / ROWS_PER_BLK; // 1024

// bf16 helpers (manual: avoid library-call overhead, values always finite)
__device__ __forceinline__ float b2f(unsigned short u) {
    return __uint_as_float(((unsigned)u) << 16);
}
__device__ __forceinline__ unsigned short f2b(float f) {
    unsigned u = __float_as_uint(f);
    return (unsigned short)((u + 0x7fffu + ((u >> 16) & 1u)) >> 16);
}

// ---------------------------------------------------------------------------
// Pass A: y1[r][o] = x[r]·(W1[o]-W2[o])  (fp32),  y2[r][o] = x[r]·W2[o] (bf16)
// Weight tiles transposed into LDS padded to stride 65 (bank-conflict-free).
// ---------------------------------------------------------------------------
__global__ __launch_bounds__(256) void pass_a(const float* __restrict__ x,
                                              const float* __restrict__ w,
                                              float* __restrict__ y1,
                                              unsigned short* __restrict__ y2) {
    __shared__ float w1m[64 * 65];  // [c][o] = (W1-W2)^T, padded
    __shared__ float w2s[64 * 65];  // [c][o] = W2^T, padded
    __shared__ float xs[64 * 64];   // [r][c]
    const int tid = threadIdx.x;

    for (int i = tid; i < 64 * 64; i += 256) {
        int o = i >> 6, c = i & 63;
        float a = w[o * 128 + c];        // W1[o][c]
        float b = w[o * 128 + 64 + c];   // W2[o][c]
        w1m[c * 65 + o] = a - b;
        w2s[c * 65 + o] = b;
    }
    const long base = (long)blockIdx.x * ROWS_PER_BLK;
    const float* xsrc = x + base * 64;
    for (int i = tid; i < 64 * 64; i += 256) xs[i] = xsrc[i];
    __syncthreads();

    const int o  = tid & 63;
    const int rr = tid >> 6;  // 0..3
    for (int chunk = 0; chunk < 4; ++chunk) {
        const int r0 = chunk * 16 + rr * 4;
        float a1[4] = {0.f, 0.f, 0.f, 0.f};
        float a2[4] = {0.f, 0.f, 0.f, 0.f};
        for (int c4 = 0; c4 < 16; ++c4) {
            float4 xv[4];
#pragma unroll
            for (int j = 0; j < 4; ++j)
                xv[j] = *(const float4*)&xs[(r0 + j) * 64 + c4 * 4];
#pragma unroll
            for (int cc = 0; cc < 4; ++cc) {
                const int c = c4 * 4 + cc;
                const float wv1 = w1m[c * 65 + o];
                const float wv2 = w2s[c * 65 + o];
                const float xj0 = (&xv[0].x)[cc], xj1 = (&xv[1].x)[cc];
                const float xj2 = (&xv[2].x)[cc], xj3 = (&xv[3].x)[cc];
                a1[0] = fmaf(xj0, wv1, a1[0]); a2[0] = fmaf(xj0, wv2, a2[0]);
                a1[1] = fmaf(xj1, wv1, a1[1]); a2[1] = fmaf(xj1, wv2, a2[1]);
                a1[2] = fmaf(xj2, wv1, a1[2]); a2[2] = fmaf(xj2, wv2, a2[2]);
                a1[3] = fmaf(xj3, wv1, a1[3]); a2[3] = fmaf(xj3, wv2, a2[3]);
            }
        }
#pragma unroll
        for (int j = 0; j < 4; ++j) {
            y1[(base + r0 + j) * 64 + o] = a1[j];
            y2[(base + r0 + j) * 64 + o] = f2b(a2[j]);
        }
    }
}

// ---------------------------------------------------------------------------
// Pass B: h = y1[row] + b2f(y2[b][idx]); per-row signed extremum over k=16
// (gamma sign folded: e = s*h, butterfly max over ksub lanes, ext = s*e) and
// per-channel sum/sumsq partials. y2 is bf16: per-batch slice is 2.1 MB --
// fits one XCD L2. Block->XCD-affine remap keeps each XCD in one slice.
// Lane layout: lane = ksub*16 + c4; ushort4 gathers (512 B per wave-instr).
// ---------------------------------------------------------------------------
__global__ __launch_bounds__(256) void pass_b(const float* __restrict__ y1,
                                              const unsigned short* __restrict__ y2,
                                              const int* __restrict__ idx,
                                              const float* __restrict__ gamma,
                                              unsigned short* __restrict__ exth,
                                              float* __restrict__ partial) {
    __shared__ int sidx[ROWS_PER_BLK * K_];  // 1024 ints
    __shared__ float reds[4][64];
    __shared__ float redq[4][64];
    const int tid = threadIdx.x;
    const int blk = blockIdx.x;
    const int xcd = blk & 7;
    const int bt = xcd >> 1;                         // batch for this XCD pair
    const int slot = ((blk >> 3) << 1) | (xcd & 1);  // 0..255 within batch
    const long base = (long)bt * N_ + (long)slot * ROWS_PER_BLK;

    ((int4*)sidx)[tid] = ((const int4*)(idx + base * K_))[tid];

    const int lane = tid & 63;
    const int wv   = tid >> 6;   // wave 0..3
    const int ksub = lane >> 4;  // 0..3
    const int c4   = lane & 15;  // channel quad: channels 4*c4..4*c4+3
    const unsigned short* y2b = y2 + (long)bt * N_ * 64;

    const float4 gm = ((const float4*)gamma)[c4];
    const float4 sgn = make_float4(gm.x >= 0.f ? 1.f : -1.f,
                                   gm.y >= 0.f ? 1.f : -1.f,
                                   gm.z >= 0.f ? 1.f : -1.f,
                                   gm.w >= 0.f ? 1.f : -1.f);
    __syncthreads();

    float4 psum = make_float4(0.f, 0.f, 0.f, 0.f);
    float4 psq  = make_float4(0.f, 0.f, 0.f, 0.f);

    for (int rl = wv; rl < ROWS_PER_BLK; rl += 4) {  // 16 rows per wave
        const long row = base + rl;
        const float4 y1v = ((const float4*)(y1 + row * 64))[c4];
        float4 e = make_float4(-3.402823466e+38f, -3.402823466e+38f,
                               -3.402823466e+38f, -3.402823466e+38f);
#pragma unroll
        for (int kk = 0; kk < 4; ++kk) {
            const int m = sidx[rl * K_ + kk * 4 + ksub];
            const ushort4 v = *(const ushort4*)(y2b + (long)m * 64 + c4 * 4);
            const float hx = y1v.x + b2f(v.x), hy = y1v.y + b2f(v.y);
            const float hz = y1v.z + b2f(v.z), hw = y1v.w + b2f(v.w);
            e.x = fmaxf(e.x, sgn.x * hx); e.y = fmaxf(e.y, sgn.y * hy);
            e.z = fmaxf(e.z, sgn.z * hz); e.w = fmaxf(e.w, sgn.w * hw);
            psum.x += hx; psum.y += hy; psum.z += hz; psum.w += hw;
            psq.x = fmaf(hx, hx, psq.x); psq.y = fmaf(hy, hy, psq.y);
            psq.z = fmaf(hz, hz, psq.z); psq.w = fmaf(hw, hw, psq.w);
        }
        // reduce over the 4 ksub groups (lanes 16 apart)
#pragma unroll
        for (int d = 16; d <= 32; d <<= 1) {
            e.x = fmaxf(e.x, __shfl_xor(e.x, d));
            e.y = fmaxf(e.y, __shfl_xor(e.y, d));
            e.z = fmaxf(e.z, __shfl_xor(e.z, d));
            e.w = fmaxf(e.w, __shfl_xor(e.w, d));
        }
        if (ksub == 0) {
            ushort4 r;
            r.x = f2b(sgn.x * e.x); r.y = f2b(sgn.y * e.y);
            r.z = f2b(sgn.z * e.z); r.w = f2b(sgn.w * e.w);
            *(ushort4*)(exth + row * 64 + c4 * 4) = r;
        }
    }
    // reduce per-lane partial sums over ksub groups
#pragma unroll
    for (int d = 16; d <= 32; d <<= 1) {
        psum.x += __shfl_xor(psum.x, d); psum.y += __shfl_xor(psum.y, d);
        psum.z += __shfl_xor(psum.z, d); psum.w += __shfl_xor(psum.w, d);
        psq.x  += __shfl_xor(psq.x, d);  psq.y  += __shfl_xor(psq.y, d);
        psq.z  += __shfl_xor(psq.z, d);  psq.w  += __shfl_xor(psq.w, d);
    }
    if (ksub == 0) {
        *(float4*)&reds[wv][c4 * 4] = psum;
        *(float4*)&redq[wv][c4 * 4] = psq;
    }
    __syncthreads();
    if (tid < 64) {
        const float s = reds[0][tid] + reds[1][tid] + reds[2][tid] + reds[3][tid];
        const float q = redq[0][tid] + redq[1][tid] + redq[2][tid] + redq[3][tid];
        partial[blk * 128 + tid] = s;
        partial[blk * 128 + 64 + tid] = q;
    }
}

// ---------------------------------------------------------------------------
// Pass C: 64 blocks, one per channel; double-precision reduction of the
// 1024 block partials; emits scale/shift.
// ---------------------------------------------------------------------------
__global__ __launch_bounds__(256) void pass_c(const float* __restrict__ partial,
                                              const float* __restrict__ gamma,
                                              const float* __restrict__ beta,
                                              float* __restrict__ ss) {
    __shared__ double rs[256];
    __shared__ double rq[256];
    const int o = blockIdx.x;
    const int tid = threadIdx.x;
    double as = 0.0, aq = 0.0;
    for (int i = tid; i < NBLK_AB; i += 256) {
        as += (double)partial[i * 128 + o];
        aq += (double)partial[i * 128 + 64 + o];
    }
    rs[tid] = as;
    rq[tid] = aq;
    __syncthreads();
    for (int s = 128; s > 0; s >>= 1) {
        if (tid < s) { rs[tid] += rs[tid + s]; rq[tid] += rq[tid + s]; }
        __syncthreads();
    }
    if (tid == 0) {
        const double cnt = (double)B_ * N_ * K_;  // 1,048,576
        double mean = rs[0] / cnt;
        double var = rq[0] / cnt - mean * mean;
        float scale = gamma[o] * (float)(1.0 / sqrt(var + (double)BN_EPS));
        float shift = beta[o] - (float)mean * scale;
        ss[o] = scale;
        ss[64 + o] = shift;
    }
}

// ---------------------------------------------------------------------------
// Pass D: out = relu(scale * exth + shift); exth is bf16 (8 elts per thread).
// FIX vs R4: r[8] is a real array (the float4-pair aliasing was UB -> odd
// float4s of output were garbage).
// ---------------------------------------------------------------------------
__global__ __launch_bounds__(256) void pass_d(const unsigned short* __restrict__ exth,
                                              const float* __restrict__ ss,
                                              float* __restrict__ out) {
    __shared__ float sscale[64], sshift[64];
    const int tid = threadIdx.x;
    if (tid < 64) { sscale[tid] = ss[tid]; sshift[tid] = ss[64 + tid]; }
    __syncthreads();
    const uint4* ep = (const uint4*)exth;   // 8 bf16 per uint4
    const long total8 = (long)ROWS * 64 / 8;  // 524,288
    for (long i = (long)blockIdx.x * 256 + tid; i < total8;
         i += (long)gridDim.x * 256) {
        const int c0 = ((int)i * 8) & 63;
        const uint4 u = ep[i];
        const unsigned uu[4] = {u.x, u.y, u.z, u.w};
        float r[8];
#pragma unroll
        for (int j = 0; j < 4; ++j) {
            const float e0 = __uint_as_float(uu[j] << 16);
            const float e1 = __uint_as_float(uu[j] & 0xffff0000u);
            r[2 * j]     = fmaxf(fmaf(sscale[c0 + 2 * j],     e0, sshift[c0 + 2 * j]),     0.f);
            r[2 * j + 1] = fmaxf(fmaf(sscale[c0 + 2 * j + 1], e1, sshift[c0 + 2 * j + 1]), 0.f);
        }
        ((float4*)out)[2 * i]     = make_float4(r[0], r[1], r[2], r[3]);
        ((float4*)out)[2 * i + 1] = make_float4(r[4], r[5], r[6], r[7]);
    }
}

extern "C" void kernel_launch(void* const* d_in, const int* in_sizes, int n_in,
                              void* d_out, int out_size, void* d_ws, size_t ws_size,
                              hipStream_t stream) {
    const float* x     = (const float*)d_in[0];
    const int*   idx   = (const int*)d_in[1];
    const float* w     = (const float*)d_in[2];
    const float* gamma = (const float*)d_in[3];
    const float* beta  = (const float*)d_in[4];
    float* out = (float*)d_out;

    char* ws = (char*)d_ws;
    float*          y1      = (float*)ws;                          // 16.8 MB
    unsigned short* y2      = (unsigned short*)(ws + 16777216);    //  8.4 MB
    unsigned short* exth    = (unsigned short*)(ws + 25165824);    //  8.4 MB
    float*          partial = (float*)(ws + 33554432);             //  0.5 MB
    float*          ss      = (float*)(ws + 34078720);             //  512 B

    pass_a<<<NBLK_AB, 256, 0, stream>>>(x, w, y1, y2);
    pass_b<<<NBLK_AB, 256, 0, stream>>>(y1, y2, idx, gamma, exth, partial);
    pass_c<<<64, 256, 0, stream>>>(partial, gamma, beta, ss);
    pass_d<<<2048, 256, 0, stream>>>(exth, ss, out);
}